// Round 5
// baseline (198.607 us; speedup 1.0000x reference)
//
#include <hip/hip_runtime.h>
#include <hip/hip_bf16.h>

typedef __attribute__((ext_vector_type(8))) __bf16 bf16x8;
typedef __attribute__((ext_vector_type(4))) float f32x4;

#define SCALE 2.68588886f   // sqrt(5 * log2(e)); acc = 5*log2(e)*cos_sim

static __device__ __forceinline__ float fastexp2(float x) {
#if __has_builtin(__builtin_amdgcn_exp2f)
    return __builtin_amdgcn_exp2f(x);
#else
    return exp2f(x);
#endif
}

// Async 16B global->LDS (global_load_lds_dwordx4). Global side is per-lane
// (gather OK); LDS side lands at wave-uniform base + lane*16 — our lds index
// is linear in tid, so this matches exactly.
typedef __attribute__((address_space(1))) const unsigned int gu32_t;
typedef __attribute__((address_space(3))) unsigned int lu32_t;
static __device__ __forceinline__ void load16_to_lds(const void* g, void* l) {
    __builtin_amdgcn_global_load_lds((gu32_t*)g, (lu32_t*)l, 16, 0, 0);
}

// ws layout (total 4,235,520 B — inside the round-1-proven 4,260,096 extent):
//   [0..33024)         float denom_parts[8256]   (one slot per sim block)
//   [33024..41216)     float pos_parts[2048]     (one slot per normalize block)
//   [41216..4235520)   __bf16 outb[16384*128]    (normalized concat, scaled)
// No atomics anywhere: every slot is written by exactly one block.

__global__ __launch_bounds__(256) void normalize_kernel(
    const float* __restrict__ x, const float* __restrict__ xa,
    __bf16* __restrict__ outb, float* __restrict__ pos_parts, int B)
{
    __shared__ float sdot[4];
    int wave = threadIdx.x >> 6;
    int lane = threadIdx.x & 63;
    int row = blockIdx.x * 4 + wave;
    const float2* px = (const float2*)(x  + (size_t)row * 128);
    const float2* pa = (const float2*)(xa + (size_t)row * 128);
    float2 v1 = px[lane];
    float2 v2 = pa[lane];
    float s1 = v1.x * v1.x + v1.y * v1.y;
    float s2 = v2.x * v2.x + v2.y * v2.y;
    float d  = v1.x * v2.x + v1.y * v2.y;
    #pragma unroll
    for (int off = 32; off; off >>= 1) {
        s1 += __shfl_xor(s1, off);
        s2 += __shfl_xor(s2, off);
        d  += __shfl_xor(d,  off);
    }
    float rn1 = rsqrtf(s1) * SCALE;
    float rn2 = rsqrtf(s2) * SCALE;
    // packed 4-B stores of two bf16
    union { __bf16 h[2]; unsigned u; } p1, p2;
    p1.h[0] = (__bf16)(v1.x * rn1); p1.h[1] = (__bf16)(v1.y * rn1);
    p2.h[0] = (__bf16)(v2.x * rn2); p2.h[1] = (__bf16)(v2.y * rn2);
    ((unsigned*)(outb + (size_t)row * 128))[lane]       = p1.u;
    ((unsigned*)(outb + (size_t)(B + row) * 128))[lane] = p2.u;
    if (lane == 0) sdot[wave] = d * rsqrtf(s1) * rsqrtf(s2);  // exact fp32 pos dot
    __syncthreads();
    if (threadIdx.x == 0)
        pos_parts[blockIdx.x] = sdot[0] + sdot[1] + sdot[2] + sdot[3];
}

// One block = one upper-triangular 128x128 tile of G = out*out^T.
// K-split staging via global_load_lds(16B): two 128x64 half-tiles (32 KB LDS).
// XOR swizzle applied on the GLOBAL side (per-lane gather), LDS side linear.
// exp2(acc) with pre-scaled inputs; mask weight via popcount; no atomics.
__global__ __launch_bounds__(256, 4) void sim_kernel(
    const __bf16* __restrict__ outb, const int* __restrict__ hq,
    const int* __restrict__ nq, float* __restrict__ denom_parts)
{
    // triangular decode: cum(b) = 128b - b(b-1)/2 tiles before tile-row b
    int t = blockIdx.x;
    int bi = (int)(128.5f - sqrtf(128.5f * 128.5f - 2.0f * (float)t));
    if (bi < 0) bi = 0;
    if (bi > 127) bi = 127;
    while (128 * (bi + 1) - ((bi + 1) * bi) / 2 <= t) ++bi;
    while (128 * bi - (bi * (bi - 1)) / 2 > t) --bi;
    int bj = bi + (t - (128 * bi - (bi * (bi - 1)) / 2));

    __shared__ __bf16 lA[128 * 64];
    __shared__ __bf16 lB[128 * 64];
    __shared__ unsigned sMU[128];   // bits_r | onehot(h_r)<<10
    __shared__ unsigned sMV[128];   // onehot(h_c) | bits_c<<10
    __shared__ float red[4];

    int tid = threadIdx.x;
    const float4* gA = (const float4*)(outb + (size_t)bi * 128 * 128);
    const float4* gB = (const float4*)(outb + (size_t)bj * 128 * 128);
    float4* sA4 = (float4*)lA;
    float4* sB4 = (float4*)lB;

    // ---- issue ph0 async staging FIRST (DMA in flight during mask build) ----
    // lds chunk ci (linear in tid -> lane*16 contiguous per wave);
    // global chunk = ci's (row, c^(row&7)) within phase column window.
    #pragma unroll
    for (int it = 0; it < 4; ++it) {
        int ci = it * 256 + tid;
        int row = ci >> 3;
        int gc = (ci & 7) ^ (row & 7);
        load16_to_lds(&gA[row * 16 + gc], &sA4[ci]);
        load16_to_lds(&gB[row * 16 + gc], &sB4[ci]);
    }

    // ---- mask build (overlaps staging latency) ----
    {
        int half = tid >> 7;
        int idx = tid & 127;
        int row = (half ? bj : bi) * 128 + idx;
        const int* p = nq + (size_t)row * 10;
        unsigned b = 0;
        #pragma unroll
        for (int k = 0; k < 10; ++k) b |= 1u << (p[k] & 31);
        unsigned h = (unsigned)hq[row];
        if (half) sMV[idx] = (1u << h) | (b << 10);
        else      sMU[idx] = b | (1u << (10 + h));
        // popc(sMU[r] & sMV[c]) = (bits_r>>h_c & 1) + (bits_c>>h_r & 1)
    }

    int wave = tid >> 6, lane = tid & 63;
    int wr = (wave >> 1) * 64;   // wave's 64x64 subtile origin
    int wc = (wave & 1) * 64;
    int lrow = lane & 15, quad = lane >> 4;

    f32x4 acc[4][4] = {};

    #pragma unroll
    for (int ph = 0; ph < 2; ++ph) {
        if (ph) {
            __syncthreads();   // ph0 reads done before overwrite
            #pragma unroll
            for (int it = 0; it < 4; ++it) {
                int ci = it * 256 + tid;
                int row = ci >> 3;
                int gc = (ci & 7) ^ (row & 7);
                load16_to_lds(&gA[row * 16 + 8 + gc], &sA4[ci]);
                load16_to_lds(&gB[row * 16 + 8 + gc], &sB4[ci]);
            }
        }
        __syncthreads();       // staged data (and masks, ph0) visible
        #pragma unroll
        for (int kk = 0; kk < 2; ++kk) {
            int chunk = kk * 4 + quad;       // local 16B chunk along k (0..7)
            bf16x8 a[4], b[4];
            #pragma unroll
            for (int m = 0; m < 4; ++m) {
                int r = wr + m * 16 + lrow;
                a[m] = *(const bf16x8*)&lA[r * 64 + ((chunk ^ (r & 7)) << 3)];
            }
            #pragma unroll
            for (int n = 0; n < 4; ++n) {
                int r = wc + n * 16 + lrow;
                b[n] = *(const bf16x8*)&lB[r * 64 + ((chunk ^ (r & 7)) << 3)];
            }
            #pragma unroll
            for (int m = 0; m < 4; ++m)
                #pragma unroll
                for (int n = 0; n < 4; ++n)
                    acc[m][n] = __builtin_amdgcn_mfma_f32_16x16x32_bf16(
                        a[m], b[n], acc[m][n], 0, 0, 0);
        }
    }

    // Hoist masks to registers (C/D layout: col = lane&15, row = quad*4+reg).
    unsigned mv[4], mu[4][4];
    #pragma unroll
    for (int n = 0; n < 4; ++n) mv[n] = sMV[wc + n * 16 + lrow];
    #pragma unroll
    for (int m = 0; m < 4; ++m)
        #pragma unroll
        for (int r = 0; r < 4; ++r) mu[m][r] = sMU[wr + m * 16 + quad * 4 + r];

    float ls[4] = {0.0f, 0.0f, 0.0f, 0.0f};   // 4 chains: break fmac latency
    float lsum;
    if (bi != bj) {            // uniform branch: clean epilogue for 98.5% blocks
        #pragma unroll
        for (int m = 0; m < 4; ++m)
            #pragma unroll
            for (int n = 0; n < 4; ++n)
                #pragma unroll
                for (int r = 0; r < 4; ++r)
                    ls[r] += fastexp2(acc[m][n][r]) *
                             (float)__popc(mu[m][r] & mv[n]);
        lsum = (ls[0] + ls[1]) + (ls[2] + ls[3]);
    } else {
        #pragma unroll
        for (int m = 0; m < 4; ++m) {
            #pragma unroll
            for (int n = 0; n < 4; ++n) {
                #pragma unroll
                for (int r = 0; r < 4; ++r) {
                    float w = (float)__popc(mu[m][r] & mv[n]);
                    if ((wr + m * 16 + quad * 4 + r) == (wc + n * 16 + lrow))
                        w = 0.0f;
                    ls[r] += fastexp2(acc[m][n][r]) * w;
                }
            }
        }
        lsum = ((ls[0] + ls[1]) + (ls[2] + ls[3])) * 0.5f;  // pairs counted 2x
    }

    #pragma unroll
    for (int off = 32; off; off >>= 1) lsum += __shfl_down(lsum, off);
    if (lane == 0) red[wave] = lsum;
    __syncthreads();
    if (tid == 0)
        denom_parts[blockIdx.x] = red[0] + red[1] + red[2] + red[3];
}

__global__ __launch_bounds__(1024) void finalize_kernel(
    const float* __restrict__ denom_parts, const float* __restrict__ pos_parts,
    float* __restrict__ out, float invB, int nd, int np)
{
    __shared__ float sred[32];
    int tid = threadIdx.x;
    float d = 0.0f, p = 0.0f;
    for (int i = tid; i < nd; i += 1024) d += denom_parts[i];
    for (int i = tid; i < np; i += 1024) p += pos_parts[i];
    #pragma unroll
    for (int off = 32; off; off >>= 1) {
        d += __shfl_down(d, off);
        p += __shfl_down(p, off);
    }
    int wv = tid >> 6, ln = tid & 63;
    if (ln == 0) { sred[wv] = d; sred[16 + wv] = p; }
    __syncthreads();
    if (tid == 0) {
        float D = 0.0f, P = 0.0f;
        #pragma unroll
        for (int i = 0; i < 16; ++i) { D += sred[i]; P += sred[16 + i]; }
        out[0] = logf(D) - 5.0f * P * invB;
    }
}

extern "C" void kernel_launch(void* const* d_in, const int* in_sizes, int n_in,
                              void* d_out, int out_size, void* d_ws, size_t ws_size,
                              hipStream_t stream) {
    const float* x  = (const float*)d_in[0];
    const float* xa = (const float*)d_in[1];
    const int* hq   = (const int*)d_in[2];
    const int* nq   = (const int*)d_in[3];
    int B = in_sizes[0] / 128;   // 8192
    int N = 2 * B;               // 16384
    int T = N / 128;             // 128 tile-rows
    int nblocks = T * (T + 1) / 2;   // 8256 upper-triangular tiles

    char* ws = (char*)d_ws;
    float* denom_parts = (float*)ws;                       // 8256 f32
    float* pos_parts   = (float*)(ws + 33024);             // 2048 f32
    __bf16* outb       = (__bf16*)(ws + 41216);            // N*128 bf16

    normalize_kernel<<<B / 4, 256, 0, stream>>>(x, xa, outb, pos_parts, B);
    sim_kernel<<<nblocks, 256, 0, stream>>>(outb, hq, nq, denom_parts);
    finalize_kernel<<<1, 1024, 0, stream>>>(denom_parts, pos_parts,
                                            (float*)d_out, 1.0f / (float)B,
                                            nblocks, B / 4);
}